// Round 5
// baseline (11.296 us; speedup 1.0000x reference)
//
#include <hip/hip_runtime.h>
#include <hip/hip_bf16.h>
#include <math.h>

// Problem constants: B=256, H=32, S=16, D=128
#define NB 256
#define NH 32
#define NS 16
#define ND 128

// One 64-lane wave per block handles TWO consecutive rows (rows 2p,2p+1 share
// batch b, so split geometry is wave-uniform). Each half-wave (32 lanes) owns
// one row; each lane one float4 (16B). Valid splits form a prefix s<nvalid.
// Loads/FMAs are issued in GROUPS of 4 guarded by wave-uniform branches;
// within the last active group, indices are clamped (<=3 duplicate loads,
// nullified by w[s]==0). This keeps the load stream nearly minimal while
// avoiding any jump table / deep control flow.
__global__ __launch_bounds__(64) void merge_splits_kernel(
    const float* __restrict__ att_out,    // [B,H,S,D]
    const float* __restrict__ att_lse,    // [B,H,S]
    const int*   __restrict__ kv_indptr,  // [B+1]
    const int*   __restrict__ num_splits, // [B]
    float*       __restrict__ out)        // [B,H,D]
{
    const int lane = threadIdx.x;             // 0..63
    const int half = lane >> 5;               // which of the 2 rows
    const int l    = lane & 31;               // float4 index within row
    const int row  = blockIdx.x * 2 + half;   // b*NH + h
    const int b    = row >> 5;                // NH == 32 (uniform per block)

    // Wave-uniform split geometry
    const int seq_len = kv_indptr[b + 1] - kv_indptr[b];
    const int splits  = num_splits[b];
    int ps = (seq_len + splits - 1) / splits;         // cdiv
    ps = ((ps + 31) >> 5) << 5;                       // round up to 32
    const int nvalid = (seq_len + ps - 1) / ps;       // 1..16 (prefix of valid splits)
    const int nvm1   = nvalid - 1;

    // LSE row: 16 floats as 4x float4 (issued first; in flight with att loads)
    const float4* lse4 = (const float4*)(att_lse + (size_t)row * NS);
    const float4 L0 = lse4[0], L1 = lse4[1], L2 = lse4[2], L3 = lse4[3];

    // Loads in groups of 4 (uniform guard per group; clamp within group).
    const float4* __restrict__ src =
        (const float4*)(att_out + (size_t)row * NS * ND);
    float4 v[NS];
#pragma unroll
    for (int g = 0; g < 4; ++g) {
        if (g * 4 < nvalid) {                         // wave-uniform branch
#pragma unroll
            for (int s = g * 4; s < g * 4 + 4; ++s) {
                const int sc = (s < nvalid) ? s : nvm1;   // uniform s_cselect
                v[s] = src[sc * (ND / 4) + l];
            }
        }
    }

    // Softmax weights over the valid prefix (overlaps load latency).
    float w[NS] = {L0.x, L0.y, L0.z, L0.w, L1.x, L1.y, L1.z, L1.w,
                   L2.x, L2.y, L2.z, L2.w, L3.x, L3.y, L3.z, L3.w};
    float m = -INFINITY;
#pragma unroll
    for (int s = 0; s < NS; ++s) {
        const float li = (s < nvalid) ? w[s] : -INFINITY;
        w[s] = li;
        m = fmaxf(m, li);
    }
    float esum = 0.f;
#pragma unroll
    for (int s = 0; s < NS; ++s) {
        w[s] = __expf(w[s] - m);     // exp(-inf) == 0 for invalid splits
        esum += w[s];
    }

    // FMAs in the same groups of 4 (skipped groups' v[] never read).
    float4 acc = make_float4(0.f, 0.f, 0.f, 0.f);
#pragma unroll
    for (int g = 0; g < 4; ++g) {
        if (g * 4 < nvalid) {                         // wave-uniform branch
#pragma unroll
            for (int s = g * 4; s < g * 4 + 4; ++s) {
                acc.x = fmaf(w[s], v[s].x, acc.x);
                acc.y = fmaf(w[s], v[s].y, acc.y);
                acc.z = fmaf(w[s], v[s].z, acc.z);
                acc.w = fmaf(w[s], v[s].w, acc.w);
            }
        }
    }

    const float inv = 1.f / esum;
    float4* dst = (float4*)(out + (size_t)row * ND);
    dst[l] = make_float4(acc.x * inv, acc.y * inv, acc.z * inv, acc.w * inv);
}

extern "C" void kernel_launch(void* const* d_in, const int* in_sizes, int n_in,
                              void* d_out, int out_size, void* d_ws, size_t ws_size,
                              hipStream_t stream) {
    const float* att_out    = (const float*)d_in[0];
    const float* att_lse    = (const float*)d_in[1];
    // d_in[2] = q (unused), d_in[3] = v_buffer (unused)
    const int*   kv_indptr  = (const int*)d_in[4];
    const int*   num_splits = (const int*)d_in[5];
    float* out = (float*)d_out;

    const int pairs = NB * NH / 2;            // 4096 row-pairs, 64 threads each
    merge_splits_kernel<<<pairs, 64, 0, stream>>>(
        att_out, att_lse, kv_indptr, num_splits, out);
}

// Round 6
// 10.917 us; speedup vs baseline: 1.0346x; 1.0346x over previous
//
#include <hip/hip_runtime.h>
#include <hip/hip_bf16.h>
#include <math.h>

// Problem constants: B=256, H=32, S=16, D=128
#define NB 256
#define NH 32
#define NS 16
#define ND 128

// One 64-lane wave per ROW (8192 waves = 8 waves/SIMD -> latency-hiding).
// Lanes cover a SPLIT PAIR per load: half = lane>>5 selects split parity,
// l = lane&31 the float4 within D=128. Each load instruction moves 1 KiB
// (64 lanes x 16 B). v[8] keeps VGPRs <= 64 (the 8-waves/EU threshold,
// enforced via __launch_bounds__(256, 8)). Each half-wave accumulates its
// parity's splits; one __shfl_xor(...,32) merges parities for acc and esum.
__global__ __launch_bounds__(256, 8) void merge_splits_kernel(
    const float* __restrict__ att_out,    // [B,H,S,D]
    const float* __restrict__ att_lse,    // [B,H,S]
    const int*   __restrict__ kv_indptr,  // [B+1]
    const int*   __restrict__ num_splits, // [B]
    float*       __restrict__ out)        // [B,H,D]
{
    const int tid  = threadIdx.x;
    const int wid  = tid >> 6;                // wave in block: 0..3
    const int lane = tid & 63;
    const int half = lane >> 5;               // split parity (0: even, 1: odd)
    const int l    = lane & 31;               // float4 index within D
    const int row  = blockIdx.x * 4 + wid;    // b*NH + h
    const int b    = row >> 5;                // NH == 32 (wave-uniform)

    // Wave-uniform split geometry
    const int seq_len = kv_indptr[b + 1] - kv_indptr[b];
    const int splits  = num_splits[b];
    int ps = (seq_len + splits - 1) / splits;         // cdiv
    ps = ((ps + 31) >> 5) << 5;                       // round up to 32
    const int nvalid = (seq_len + ps - 1) / ps;       // 1..16 (prefix of valid splits)
    const int nvm1   = nvalid - 1;

    // LSE row (16 floats, broadcast) — issued first, in flight with att loads
    const float4* lse4 = (const float4*)(att_lse + (size_t)row * NS);
    const float4 L0 = lse4[0], L1 = lse4[1], L2 = lse4[2], L3 = lse4[3];

    // att loads: pair-group p covers splits {2p, 2p+1}; issue iff 2p < nvalid
    // (uniform guard); clamp the odd half's index (duplicate gets weight 0).
    const float4* __restrict__ src =
        (const float4*)(att_out + (size_t)row * NS * ND);
    float4 v[8];
#pragma unroll
    for (int p = 0; p < 8; ++p) {
        if (2 * p < nvalid) {                         // wave-uniform branch
            const int sp = 2 * p + half;
            const int sc = (sp <= nvm1) ? sp : nvm1;  // per-lane cndmask on addr
            v[p] = src[sc * (ND / 4) + l];
        }
    }

    // Parity-partial softmax: this half-wave's weights w[p] = lse[2p+half]
    float w[8];
    w[0] = half ? L0.y : L0.x;  w[1] = half ? L0.w : L0.z;
    w[2] = half ? L1.y : L1.x;  w[3] = half ? L1.w : L1.z;
    w[4] = half ? L2.y : L2.x;  w[5] = half ? L2.w : L2.z;
    w[6] = half ? L3.y : L3.x;  w[7] = half ? L3.w : L3.z;

    float m = -INFINITY;
#pragma unroll
    for (int p = 0; p < 8; ++p) {
        const float li = (2 * p + half < nvalid) ? w[p] : -INFINITY;
        w[p] = li;
        m = fmaxf(m, li);
    }
    m = fmaxf(m, __shfl_xor(m, 32));      // full-row max across parities

    float esum = 0.f;
#pragma unroll
    for (int p = 0; p < 8; ++p) {
        w[p] = __expf(w[p] - m);          // exp(-inf) == 0 for invalid/dup splits
        esum += w[p];
    }

    // Parity-partial weighted sum (guards match the load groups).
    float4 acc = make_float4(0.f, 0.f, 0.f, 0.f);
#pragma unroll
    for (int p = 0; p < 8; ++p) {
        if (2 * p < nvalid) {
            acc.x = fmaf(w[p], v[p].x, acc.x);
            acc.y = fmaf(w[p], v[p].y, acc.y);
            acc.z = fmaf(w[p], v[p].z, acc.z);
            acc.w = fmaf(w[p], v[p].w, acc.w);
        }
    }

    // Merge parities (lane i <-> lane i+32) for esum and acc.
    esum  += __shfl_xor(esum, 32);
    acc.x += __shfl_xor(acc.x, 32);
    acc.y += __shfl_xor(acc.y, 32);
    acc.z += __shfl_xor(acc.z, 32);
    acc.w += __shfl_xor(acc.w, 32);

    if (half == 0) {                       // lower half-wave writes the row
        const float inv = 1.f / esum;
        float4* dst = (float4*)(out + (size_t)row * ND);
        dst[l] = make_float4(acc.x * inv, acc.y * inv, acc.z * inv, acc.w * inv);
    }
}

extern "C" void kernel_launch(void* const* d_in, const int* in_sizes, int n_in,
                              void* d_out, int out_size, void* d_ws, size_t ws_size,
                              hipStream_t stream) {
    const float* att_out    = (const float*)d_in[0];
    const float* att_lse    = (const float*)d_in[1];
    // d_in[2] = q (unused), d_in[3] = v_buffer (unused)
    const int*   kv_indptr  = (const int*)d_in[4];
    const int*   num_splits = (const int*)d_in[5];
    float* out = (float*)d_out;

    const int rows = NB * NH;                 // 8192 rows, 1 wave each
    const int blocks = rows / 4;              // 2048 blocks x 256 threads
    merge_splits_kernel<<<blocks, 256, 0, stream>>>(
        att_out, att_lse, kv_indptr, num_splits, out);
}